// Round 4
// baseline (1688.705 us; speedup 1.0000x reference)
//
#include <hip/hip_runtime.h>

// EntityLinker fused edge-MLP for MI355X (gfx950).
// Round 4: occupancy over ILP. LDS halved by storing only [hi|hj] and
// synthesizing diff/product A-fragments in registers during layer 1.
//   - LDS 34.8 KB -> 4 WG/CU (16 waves/CU) via __launch_bounds__(256,4).
//   - No explicit prefetch buffers (R3 showed the compiler discards them);
//     latency hiding comes from TLP.

#define H 128

typedef __bf16 bf16x8 __attribute__((ext_vector_type(8)));
typedef float f32x4 __attribute__((ext_vector_type(4)));

__device__ __forceinline__ unsigned short f2bf(float f) {
    unsigned u = __builtin_bit_cast(unsigned, f);
    u += 0x7FFFu + ((u >> 16) & 1u);   // RNE
    return (unsigned short)(u >> 16);
}
__device__ __forceinline__ float bfhi(unsigned u) {
    return __builtin_bit_cast(float, u & 0xffff0000u);
}
__device__ __forceinline__ float bflo(unsigned u) {
    return __builtin_bit_cast(float, u << 16);
}
// combine two packed-bf16 pairs: |a-b| (isdiff) or a*b, repacked to bf16x2
__device__ __forceinline__ unsigned comb(unsigned ua, unsigned ub, bool isdiff) {
    float a0 = bflo(ua), a1 = bfhi(ua);
    float b0 = bflo(ub), b1 = bfhi(ub);
    float r0 = isdiff ? fabsf(a0 - b0) : a0 * b0;
    float r1 = isdiff ? fabsf(a1 - b1) : a1 * b1;
    return (unsigned)f2bf(r0) | ((unsigned)f2bf(r1) << 16);
}

__global__ void prep_w1(const float* __restrict__ W1, unsigned short* __restrict__ W1T) {
    int idx = blockIdx.x * 256 + threadIdx.x;      // 131072
    int n = idx >> 9;
    int k = idx & 511;
    W1T[idx] = f2bf(W1[k * 256 + n]);              // W1 is [512][256] (in,out)
}

__global__ void prep_w2(const float* __restrict__ W2, unsigned short* __restrict__ W2T) {
    int idx = blockIdx.x * 256 + threadIdx.x;      // 32768
    int n = idx >> 8;
    int k = idx & 255;
    W2T[idx] = f2bf(W2[k * 128 + n]);              // W2 is [256][128]
}

__launch_bounds__(256, 4)
__global__ void fused_mlp(const float* __restrict__ node,
                          const int* __restrict__ src,
                          const int* __restrict__ dst,
                          const unsigned short* __restrict__ W1T,  // [256][512] bf16
                          const float* __restrict__ b1,
                          const unsigned short* __restrict__ W2T,  // [128][256] bf16
                          const float* __restrict__ b2,
                          const float* __restrict__ W3,            // [128][2] f32
                          const float* __restrict__ b3,
                          float* __restrict__ out,                 // [E][2] f32
                          int E) {
    // sH row (stride 264 shorts = 132 dw, 132%32=4 -> 2-way conflicts = free):
    //   hi at cols 0..127, hj at cols 136..263 (136*2B = 272B, 16B aligned).
    // Overlays: x1 [64][264] (cols 0..255) after layer 1; x2 [64][136] after layer 2.
    __shared__ __align__(16) unsigned short sH[64 * 264];   // 33792 B
    __shared__ __align__(16) float sW3[256];                // [c][128] de-interleaved

    const int t = threadIdx.x;
    const int e0 = blockIdx.x * 64;

    const int lane = t & 63;
    const int wv = t >> 6;
    const int quad = lane >> 4;
    const int lrow = lane & 15;
    const int nb = wv * 64;        // layer-1 N-slice
    const int nb2 = wv * 32;       // layer-2 N-slice

    // ---------------- Phase A: gather hi/hj -> LDS (bf16) ----------------
    {
        int r = t >> 2;            // edge row 0..63
        int p = t & 3;             // 32-col quarter
        int e = e0 + r;
        int ec = e < E ? e : (E - 1);
        const float* hi = node + (long)src[ec] * H + p * 32;
        const float* hj = node + (long)dst[ec] * H + p * 32;
        unsigned short* rowp = sH + r * 264;
#pragma unroll
        for (int b = 0; b < 8; b++) {
            float4 a = ((const float4*)hi)[b];
            float4 c = ((const float4*)hj)[b];
            int c0 = p * 32 + b * 4;
            ushort4 wa, wc;
            wa.x = f2bf(a.x); wa.y = f2bf(a.y); wa.z = f2bf(a.z); wa.w = f2bf(a.w);
            wc.x = f2bf(c.x); wc.y = f2bf(c.y); wc.z = f2bf(c.z); wc.w = f2bf(c.w);
            *(ushort4*)(rowp + c0)       = wa;
            *(ushort4*)(rowp + 136 + c0) = wc;
        }
        sW3[(t & 1) * 128 + (t >> 1)] = W3[t];   // [k][c] -> [c][k]
    }
    __syncthreads();               // hi/hj visible

    // ---------------- Phase B: layer 1 (M=64, N=256, K=512) ----------------
    const unsigned short* w1p[4];
#pragma unroll
    for (int nt = 0; nt < 4; nt++) w1p[nt] = W1T + (nb + nt * 16 + lrow) * 512 + quad * 8;

    f32x4 acc[4][4];
#pragma unroll
    for (int mt = 0; mt < 4; mt++)
#pragma unroll
        for (int nt = 0; nt < 4; nt++)
            acc[mt][nt] = (f32x4){0.f, 0.f, 0.f, 0.f};

    const unsigned short* rowA[4];
#pragma unroll
    for (int mt = 0; mt < 4; mt++) rowA[mt] = sH + (mt * 16 + lrow) * 264 + quad * 8;

#pragma unroll
    for (int ks = 0; ks < 16; ks++) {
        bf16x8 av[4], bv[4];
#pragma unroll
        for (int nt = 0; nt < 4; nt++) bv[nt] = *(const bf16x8*)(w1p[nt] + ks * 32);
        if (ks < 4) {                                   // hi chunk
#pragma unroll
            for (int mt = 0; mt < 4; mt++)
                av[mt] = *(const bf16x8*)(rowA[mt] + ks * 32);
        } else if (ks < 8) {                            // hj chunk
#pragma unroll
            for (int mt = 0; mt < 4; mt++)
                av[mt] = *(const bf16x8*)(rowA[mt] + 136 + (ks - 4) * 32);
        } else {                                        // diff (8..11) / prod (12..15)
            const int c = (ks & 3) * 32;
            const bool isdiff = ks < 12;
#pragma unroll
            for (int mt = 0; mt < 4; mt++) {
                uint4 ua = *(const uint4*)(rowA[mt] + c);
                uint4 ub = *(const uint4*)(rowA[mt] + 136 + c);
                uint4 rr;
                rr.x = comb(ua.x, ub.x, isdiff);
                rr.y = comb(ua.y, ub.y, isdiff);
                rr.z = comb(ua.z, ub.z, isdiff);
                rr.w = comb(ua.w, ub.w, isdiff);
                av[mt] = __builtin_bit_cast(bf16x8, rr);
            }
        }
#pragma unroll
        for (int mt = 0; mt < 4; mt++)
#pragma unroll
            for (int nt = 0; nt < 4; nt++)
                acc[mt][nt] = __builtin_amdgcn_mfma_f32_16x16x32_bf16(av[mt], bv[nt], acc[mt][nt], 0, 0, 0);
    }

    // ---------------- Phase C: relu+bias -> x1 bf16 (overlay sH) ----------------
    float b1v[4];
#pragma unroll
    for (int nt = 0; nt < 4; nt++) b1v[nt] = b1[nb + nt * 16 + lrow];

    __syncthreads();               // all layer-1 reads of sH done
    unsigned short* sx1 = sH;      // [64][264], cols 0..255
#pragma unroll
    for (int mt = 0; mt < 4; mt++)
#pragma unroll
        for (int nt = 0; nt < 4; nt++)
#pragma unroll
            for (int i = 0; i < 4; i++) {
                int row = mt * 16 + quad * 4 + i;    // C/D: row = quad*4 + reg
                int col = nb + nt * 16 + lrow;       //      col = lane&15
                float v = acc[mt][nt][i] + b1v[nt];
                v = v > 0.f ? v : 0.f;
                sx1[row * 264 + col] = f2bf(v);
            }
    __syncthreads();               // x1 complete

    // ---------------- Phase D: layer 2 (M=64, N=128, K=256) ----------------
    const unsigned short* w2p[2];
#pragma unroll
    for (int nt = 0; nt < 2; nt++) w2p[nt] = W2T + (nb2 + nt * 16 + lrow) * 256 + quad * 8;

    f32x4 acc2[4][2];
#pragma unroll
    for (int mt = 0; mt < 4; mt++)
#pragma unroll
        for (int nt = 0; nt < 2; nt++)
            acc2[mt][nt] = (f32x4){0.f, 0.f, 0.f, 0.f};

    const unsigned short* rowA2[4];
#pragma unroll
    for (int mt = 0; mt < 4; mt++) rowA2[mt] = sx1 + (mt * 16 + lrow) * 264 + quad * 8;

#pragma unroll
    for (int ks = 0; ks < 8; ks++) {
        bf16x8 av2[4], bv2[2];
#pragma unroll
        for (int nt = 0; nt < 2; nt++) bv2[nt] = *(const bf16x8*)(w2p[nt] + ks * 32);
#pragma unroll
        for (int mt = 0; mt < 4; mt++) av2[mt] = *(const bf16x8*)(rowA2[mt] + ks * 32);
#pragma unroll
        for (int mt = 0; mt < 4; mt++)
#pragma unroll
            for (int nt = 0; nt < 2; nt++)
                acc2[mt][nt] = __builtin_amdgcn_mfma_f32_16x16x32_bf16(av2[mt], bv2[nt], acc2[mt][nt], 0, 0, 0);
    }

    // ---------------- Phase E: relu+bias -> x2 bf16 (overlay x1) ----------------
    float b2v[2];
#pragma unroll
    for (int nt = 0; nt < 2; nt++) b2v[nt] = b2[nb2 + nt * 16 + lrow];

    __syncthreads();               // all layer-2 reads of x1 done
    unsigned short* sx2 = sH;      // [64][136] (stride 68 dw, 68%32=4 -> free)
#pragma unroll
    for (int mt = 0; mt < 4; mt++)
#pragma unroll
        for (int nt = 0; nt < 2; nt++)
#pragma unroll
            for (int i = 0; i < 4; i++) {
                int row = mt * 16 + quad * 4 + i;
                int col = nb2 + nt * 16 + lrow;
                float v = acc2[mt][nt][i] + b2v[nt];
                v = v > 0.f ? v : 0.f;
                sx2[row * 136 + col] = f2bf(v);
            }
    __syncthreads();

    // ---------------- Phase F: layer 3 (N=2), half-dots + shfl ----------------
    {
        int r = t >> 2;            // edge row 0..63
        int c = t & 1;             // class
        int h = (t >> 1) & 1;      // K-half
        const unsigned short* xr = sx2 + r * 136 + h * 64;
        const float* w3c = sW3 + c * 128 + h * 64;
        float s = 0.f;
#pragma unroll
        for (int j = 0; j < 8; j++) {
            uint4 v = *(const uint4*)(xr + j * 8);
            const float* w = w3c + j * 8;
            s += bflo(v.x) * w[0] + bfhi(v.x) * w[1]
               + bflo(v.y) * w[2] + bfhi(v.y) * w[3]
               + bflo(v.z) * w[4] + bfhi(v.z) * w[5]
               + bflo(v.w) * w[6] + bfhi(v.w) * w[7];
        }
        s += __shfl_xor(s, 2);     // combine K-halves (t^2: same r,c, other h)
        int e = e0 + r;
        if (h == 0 && e < E) out[e * 2 + c] = s + b3[c];
    }
}

extern "C" void kernel_launch(void* const* d_in, const int* in_sizes, int n_in,
                              void* d_out, int out_size, void* d_ws, size_t ws_size,
                              hipStream_t stream) {
    const float* node = (const float*)d_in[0];
    const int* src    = (const int*)d_in[1];
    const int* dst    = (const int*)d_in[2];
    const float* W1   = (const float*)d_in[3];
    const float* b1   = (const float*)d_in[4];
    const float* W2   = (const float*)d_in[5];
    const float* b2   = (const float*)d_in[6];
    const float* W3   = (const float*)d_in[7];
    const float* b3   = (const float*)d_in[8];
    float* out = (float*)d_out;
    const int E = in_sizes[1];

    unsigned short* W1T = (unsigned short*)d_ws;       // [256][512] bf16
    unsigned short* W2T = W1T + 512 * 256;             // [128][256] bf16

    hipLaunchKernelGGL(prep_w1, dim3(512), dim3(256), 0, stream, W1, W1T);
    hipLaunchKernelGGL(prep_w2, dim3(128), dim3(256), 0, stream, W2, W2T);
    const int nblk = (E + 63) / 64;
    hipLaunchKernelGGL(fused_mlp, dim3(nblk), dim3(256), 0, stream,
                       node, src, dst, W1T, b1, W2T, b2, W3, b3, out, E);
}

// Round 5
// 893.859 us; speedup vs baseline: 1.8892x; 1.8892x over previous
//
#include <hip/hip_runtime.h>

// EntityLinker fused edge-MLP for MI355X (gfx950).
// Round 5: R4's LDS-halving (store only [hi|hj], synthesize diff/prod in regs)
// but at __launch_bounds__(256,3): VGPR cap ~170 -> no spill (R4's (256,4)
// cap of 128 spilled acc to scratch: 5.4 GB HBM traffic, 1689 us).
//   - 3 WG/CU = 12 waves/CU (1.5x R3 TLP), LDS 34.8 KB.
//   - comb() cheapened: round-bias add + v_perm_b32 pack (1 instr) instead of
//     two full RNE f2bf sequences.

#define H 128

typedef __bf16 bf16x8 __attribute__((ext_vector_type(8)));
typedef float f32x4 __attribute__((ext_vector_type(4)));

__device__ __forceinline__ unsigned short f2bf(float f) {
    unsigned u = __builtin_bit_cast(unsigned, f);
    u += 0x7FFFu + ((u >> 16) & 1u);   // RNE
    return (unsigned short)(u >> 16);
}
__device__ __forceinline__ float bfhi(unsigned u) {
    return __builtin_bit_cast(float, u & 0xffff0000u);
}
__device__ __forceinline__ float bflo(unsigned u) {
    return __builtin_bit_cast(float, u << 16);
}
// combine two packed-bf16 pairs: |a-b| (isdiff) or a*b -> packed bf16x2.
// Rounding: +0x8000 bias (nearest, ties away) then take high 16 via v_perm.
__device__ __forceinline__ unsigned comb(unsigned ua, unsigned ub, bool isdiff) {
    float a0 = bflo(ua), a1 = bfhi(ua);
    float b0 = bflo(ub), b1 = bfhi(ub);
    float r0 = isdiff ? fabsf(a0 - b0) : a0 * b0;
    float r1 = isdiff ? fabsf(a1 - b1) : a1 * b1;
    unsigned u0 = __builtin_bit_cast(unsigned, r0) + 0x8000u;
    unsigned u1 = __builtin_bit_cast(unsigned, r1) + 0x8000u;
    // dst = hi16(u1) << 16 | hi16(u0)
    return __builtin_amdgcn_perm(u1, u0, 0x07060302u);
}

__global__ void prep_w1(const float* __restrict__ W1, unsigned short* __restrict__ W1T) {
    int idx = blockIdx.x * 256 + threadIdx.x;      // 131072
    int n = idx >> 9;
    int k = idx & 511;
    W1T[idx] = f2bf(W1[k * 256 + n]);              // W1 is [512][256] (in,out)
}

__global__ void prep_w2(const float* __restrict__ W2, unsigned short* __restrict__ W2T) {
    int idx = blockIdx.x * 256 + threadIdx.x;      // 32768
    int n = idx >> 8;
    int k = idx & 255;
    W2T[idx] = f2bf(W2[k * 128 + n]);              // W2 is [256][128]
}

__launch_bounds__(256, 3)
__global__ void fused_mlp(const float* __restrict__ node,
                          const int* __restrict__ src,
                          const int* __restrict__ dst,
                          const unsigned short* __restrict__ W1T,  // [256][512] bf16
                          const float* __restrict__ b1,
                          const unsigned short* __restrict__ W2T,  // [128][256] bf16
                          const float* __restrict__ b2,
                          const float* __restrict__ W3,            // [128][2] f32
                          const float* __restrict__ b3,
                          float* __restrict__ out,                 // [E][2] f32
                          int E) {
    // sH row stride 264 shorts (132 dw; 132%32=4 -> 2-way LDS aliasing = free):
    //   hi at cols 0..127, hj at cols 136..263.
    // Overlays: x1 [64][264] (cols 0..255) after layer 1; x2 [64][136] after layer 2.
    __shared__ __align__(16) unsigned short sH[64 * 264];   // 33792 B
    __shared__ __align__(16) float sW3[256];                // [c][128] de-interleaved

    const int t = threadIdx.x;
    const int e0 = blockIdx.x * 64;

    const int lane = t & 63;
    const int wv = t >> 6;
    const int quad = lane >> 4;
    const int lrow = lane & 15;
    const int nb = wv * 64;        // layer-1 N-slice
    const int nb2 = wv * 32;       // layer-2 N-slice

    // ---------------- Phase A: gather hi/hj -> LDS (bf16) ----------------
    {
        int r = t >> 2;            // edge row 0..63
        int p = t & 3;             // 32-col quarter
        int e = e0 + r;
        int ec = e < E ? e : (E - 1);
        const float* hi = node + (long)src[ec] * H + p * 32;
        const float* hj = node + (long)dst[ec] * H + p * 32;
        unsigned short* rowp = sH + r * 264;
#pragma unroll
        for (int b = 0; b < 8; b++) {
            float4 a = ((const float4*)hi)[b];
            float4 c = ((const float4*)hj)[b];
            int c0 = p * 32 + b * 4;
            ushort4 wa, wc;
            wa.x = f2bf(a.x); wa.y = f2bf(a.y); wa.z = f2bf(a.z); wa.w = f2bf(a.w);
            wc.x = f2bf(c.x); wc.y = f2bf(c.y); wc.z = f2bf(c.z); wc.w = f2bf(c.w);
            *(ushort4*)(rowp + c0)       = wa;
            *(ushort4*)(rowp + 136 + c0) = wc;
        }
        sW3[(t & 1) * 128 + (t >> 1)] = W3[t];   // [k][c] -> [c][k]
    }
    __syncthreads();               // hi/hj visible

    // ---------------- Phase B: layer 1 (M=64, N=256, K=512) ----------------
    const unsigned short* w1p[4];
#pragma unroll
    for (int nt = 0; nt < 4; nt++) w1p[nt] = W1T + (nb + nt * 16 + lrow) * 512 + quad * 8;

    f32x4 acc[4][4];
#pragma unroll
    for (int mt = 0; mt < 4; mt++)
#pragma unroll
        for (int nt = 0; nt < 4; nt++)
            acc[mt][nt] = (f32x4){0.f, 0.f, 0.f, 0.f};

    const unsigned short* rowA[4];
#pragma unroll
    for (int mt = 0; mt < 4; mt++) rowA[mt] = sH + (mt * 16 + lrow) * 264 + quad * 8;

#pragma unroll
    for (int ks = 0; ks < 16; ks++) {
        bf16x8 av[4], bv[4];
#pragma unroll
        for (int nt = 0; nt < 4; nt++) bv[nt] = *(const bf16x8*)(w1p[nt] + ks * 32);
        if (ks < 4) {                                   // hi chunk
#pragma unroll
            for (int mt = 0; mt < 4; mt++)
                av[mt] = *(const bf16x8*)(rowA[mt] + ks * 32);
        } else if (ks < 8) {                            // hj chunk
#pragma unroll
            for (int mt = 0; mt < 4; mt++)
                av[mt] = *(const bf16x8*)(rowA[mt] + 136 + (ks - 4) * 32);
        } else {                                        // diff (8..11) / prod (12..15)
            const int c = (ks & 3) * 32;
            const bool isdiff = ks < 12;
#pragma unroll
            for (int mt = 0; mt < 4; mt++) {
                uint4 ua = *(const uint4*)(rowA[mt] + c);
                uint4 ub = *(const uint4*)(rowA[mt] + 136 + c);
                uint4 rr;
                rr.x = comb(ua.x, ub.x, isdiff);
                rr.y = comb(ua.y, ub.y, isdiff);
                rr.z = comb(ua.z, ub.z, isdiff);
                rr.w = comb(ua.w, ub.w, isdiff);
                av[mt] = __builtin_bit_cast(bf16x8, rr);
            }
        }
#pragma unroll
        for (int mt = 0; mt < 4; mt++)
#pragma unroll
            for (int nt = 0; nt < 4; nt++)
                acc[mt][nt] = __builtin_amdgcn_mfma_f32_16x16x32_bf16(av[mt], bv[nt], acc[mt][nt], 0, 0, 0);
    }

    // ---------------- Phase C: relu+bias -> x1 bf16 (overlay sH) ----------------
    float b1v[4];
#pragma unroll
    for (int nt = 0; nt < 4; nt++) b1v[nt] = b1[nb + nt * 16 + lrow];

    __syncthreads();               // all layer-1 reads of sH done
    unsigned short* sx1 = sH;      // [64][264], cols 0..255
#pragma unroll
    for (int mt = 0; mt < 4; mt++)
#pragma unroll
        for (int nt = 0; nt < 4; nt++)
#pragma unroll
            for (int i = 0; i < 4; i++) {
                int row = mt * 16 + quad * 4 + i;    // C/D: row = quad*4 + reg
                int col = nb + nt * 16 + lrow;       //      col = lane&15
                float v = acc[mt][nt][i] + b1v[nt];
                v = v > 0.f ? v : 0.f;
                sx1[row * 264 + col] = f2bf(v);
            }
    __syncthreads();               // x1 complete

    // ---------------- Phase D: layer 2 (M=64, N=128, K=256) ----------------
    const unsigned short* w2p[2];
#pragma unroll
    for (int nt = 0; nt < 2; nt++) w2p[nt] = W2T + (nb2 + nt * 16 + lrow) * 256 + quad * 8;

    f32x4 acc2[4][2];
#pragma unroll
    for (int mt = 0; mt < 4; mt++)
#pragma unroll
        for (int nt = 0; nt < 2; nt++)
            acc2[mt][nt] = (f32x4){0.f, 0.f, 0.f, 0.f};

    const unsigned short* rowA2[4];
#pragma unroll
    for (int mt = 0; mt < 4; mt++) rowA2[mt] = sx1 + (mt * 16 + lrow) * 264 + quad * 8;

#pragma unroll
    for (int ks = 0; ks < 8; ks++) {
        bf16x8 av2[4], bv2[2];
#pragma unroll
        for (int nt = 0; nt < 2; nt++) bv2[nt] = *(const bf16x8*)(w2p[nt] + ks * 32);
#pragma unroll
        for (int mt = 0; mt < 4; mt++) av2[mt] = *(const bf16x8*)(rowA2[mt] + ks * 32);
#pragma unroll
        for (int mt = 0; mt < 4; mt++)
#pragma unroll
            for (int nt = 0; nt < 2; nt++)
                acc2[mt][nt] = __builtin_amdgcn_mfma_f32_16x16x32_bf16(av2[mt], bv2[nt], acc2[mt][nt], 0, 0, 0);
    }

    // ---------------- Phase E: relu+bias -> x2 bf16 (overlay x1) ----------------
    float b2v[2];
#pragma unroll
    for (int nt = 0; nt < 2; nt++) b2v[nt] = b2[nb2 + nt * 16 + lrow];

    __syncthreads();               // all layer-2 reads of x1 done
    unsigned short* sx2 = sH;      // [64][136] (stride 68 dw; 68%32=4 -> free)
#pragma unroll
    for (int mt = 0; mt < 4; mt++)
#pragma unroll
        for (int nt = 0; nt < 2; nt++)
#pragma unroll
            for (int i = 0; i < 4; i++) {
                int row = mt * 16 + quad * 4 + i;
                int col = nb2 + nt * 16 + lrow;
                float v = acc2[mt][nt][i] + b2v[nt];
                v = v > 0.f ? v : 0.f;
                sx2[row * 136 + col] = f2bf(v);
            }
    __syncthreads();

    // ---------------- Phase F: layer 3 (N=2), half-dots + shfl ----------------
    {
        int r = t >> 2;            // edge row 0..63
        int c = t & 1;             // class
        int h = (t >> 1) & 1;      // K-half
        const unsigned short* xr = sx2 + r * 136 + h * 64;
        const float* w3c = sW3 + c * 128 + h * 64;
        float s = 0.f;
#pragma unroll
        for (int j = 0; j < 8; j++) {
            uint4 v = *(const uint4*)(xr + j * 8);
            const float* w = w3c + j * 8;
            s += bflo(v.x) * w[0] + bfhi(v.x) * w[1]
               + bflo(v.y) * w[2] + bfhi(v.y) * w[3]
               + bflo(v.z) * w[4] + bfhi(v.z) * w[5]
               + bflo(v.w) * w[6] + bfhi(v.w) * w[7];
        }
        s += __shfl_xor(s, 2);     // combine K-halves (t^2: same r,c, other h)
        int e = e0 + r;
        if (h == 0 && e < E) out[e * 2 + c] = s + b3[c];
    }
}

extern "C" void kernel_launch(void* const* d_in, const int* in_sizes, int n_in,
                              void* d_out, int out_size, void* d_ws, size_t ws_size,
                              hipStream_t stream) {
    const float* node = (const float*)d_in[0];
    const int* src    = (const int*)d_in[1];
    const int* dst    = (const int*)d_in[2];
    const float* W1   = (const float*)d_in[3];
    const float* b1   = (const float*)d_in[4];
    const float* W2   = (const float*)d_in[5];
    const float* b2   = (const float*)d_in[6];
    const float* W3   = (const float*)d_in[7];
    const float* b3   = (const float*)d_in[8];
    float* out = (float*)d_out;
    const int E = in_sizes[1];

    unsigned short* W1T = (unsigned short*)d_ws;       // [256][512] bf16
    unsigned short* W2T = W1T + 512 * 256;             // [128][256] bf16

    hipLaunchKernelGGL(prep_w1, dim3(512), dim3(256), 0, stream, W1, W1T);
    hipLaunchKernelGGL(prep_w2, dim3(128), dim3(256), 0, stream, W2, W2T);
    const int nblk = (E + 63) / 64;
    hipLaunchKernelGGL(fused_mlp, dim3(nblk), dim3(256), 0, stream,
                       node, src, dst, W1T, b1, W2T, b2, W3, b3, out, E);
}

// Round 6
// 450.778 us; speedup vs baseline: 3.7462x; 1.9829x over previous
//
#include <hip/hip_runtime.h>

// EntityLinker fused edge-MLP for MI355X (gfx950).
// Round 6: M=128 edges/block at 2 WG/CU (the proven register budget).
//   - R4/R5 taught: >2 waves/EU forces in-loop spill (WRITE_SIZE GBs). So stay
//     at __launch_bounds__(256,2) and instead double per-wave MFMA density:
//     8 m-tiles x 4 n-tiles = 32 MFMAs per 4 global B-loads.
//   - K-loops kept rolled (#pragma unroll 1) to bound live registers.
//   - LDS: hi|hj only (diff/prod synthesized in regs), stride 268 -> 68.6 KB.

#define H 128

typedef __bf16 bf16x8 __attribute__((ext_vector_type(8)));
typedef float f32x4 __attribute__((ext_vector_type(4)));

__device__ __forceinline__ unsigned short f2bf(float f) {
    unsigned u = __builtin_bit_cast(unsigned, f);
    u += 0x7FFFu + ((u >> 16) & 1u);   // RNE
    return (unsigned short)(u >> 16);
}
__device__ __forceinline__ float bfhi(unsigned u) {
    return __builtin_bit_cast(float, u & 0xffff0000u);
}
__device__ __forceinline__ float bflo(unsigned u) {
    return __builtin_bit_cast(float, u << 16);
}
// |a-b| or a*b on packed bf16x2 -> packed bf16x2 (round-bias + v_perm pack)
__device__ __forceinline__ unsigned comb(unsigned ua, unsigned ub, bool isdiff) {
    float a0 = bflo(ua), a1 = bfhi(ua);
    float b0 = bflo(ub), b1 = bfhi(ub);
    float r0 = isdiff ? fabsf(a0 - b0) : a0 * b0;
    float r1 = isdiff ? fabsf(a1 - b1) : a1 * b1;
    unsigned u0 = __builtin_bit_cast(unsigned, r0) + 0x8000u;
    unsigned u1 = __builtin_bit_cast(unsigned, r1) + 0x8000u;
    return __builtin_amdgcn_perm(u1, u0, 0x07060302u);
}

__global__ void prep_w1(const float* __restrict__ W1, unsigned short* __restrict__ W1T) {
    int idx = blockIdx.x * 256 + threadIdx.x;      // 131072
    int n = idx >> 9;
    int k = idx & 511;
    W1T[idx] = f2bf(W1[k * 256 + n]);              // W1 is [512][256] (in,out)
}

__global__ void prep_w2(const float* __restrict__ W2, unsigned short* __restrict__ W2T) {
    int idx = blockIdx.x * 256 + threadIdx.x;      // 32768
    int n = idx >> 8;
    int k = idx & 255;
    W2T[idx] = f2bf(W2[k * 128 + n]);              // W2 is [256][128]
}

__launch_bounds__(256, 2)
__global__ void fused_mlp(const float* __restrict__ node,
                          const int* __restrict__ src,
                          const int* __restrict__ dst,
                          const unsigned short* __restrict__ W1T,  // [256][512] bf16
                          const float* __restrict__ b1,
                          const unsigned short* __restrict__ W2T,  // [128][256] bf16
                          const float* __restrict__ b2,
                          const float* __restrict__ W3,            // [128][2] f32
                          const float* __restrict__ b3,
                          float* __restrict__ out,                 // [E][2] f32
                          int E) {
    // sH: [128][268] bf16 (stride 134 dw, gcd(134,32)=2 -> 2-way max on row-strided
    // access = free). hi cols 0..127, hj cols 136..263.
    // Overlays: x1 [128][268] cols 0..255 after layer 1; x2 [128][140] after layer 2.
    __shared__ __align__(16) unsigned short sH[128 * 268];   // 68608 B
    __shared__ __align__(16) float sW3[256];                 // [c][128]

    const int t = threadIdx.x;
    const int e0 = blockIdx.x * 128;

    const int lane = t & 63;
    const int wv = t >> 6;
    const int quad = lane >> 4;
    const int lrow = lane & 15;
    const int nb = wv * 64;        // layer-1 N-slice
    const int nb2 = wv * 32;       // layer-2 N-slice

    // ---------------- Phase A: gather hi/hj -> LDS (bf16) ----------------
    {
        int r = t >> 1;            // edge row 0..127
        int p = t & 1;             // 64-col half
        int e = e0 + r;
        int ec = e < E ? e : (E - 1);
        const float* hi = node + (long)src[ec] * H + p * 64;
        const float* hj = node + (long)dst[ec] * H + p * 64;
        unsigned short* rowp = sH + r * 268;
#pragma unroll
        for (int b = 0; b < 16; b++) {
            float4 a = ((const float4*)hi)[b];
            float4 c = ((const float4*)hj)[b];
            int c0 = p * 64 + b * 4;
            ushort4 wa, wc;
            wa.x = f2bf(a.x); wa.y = f2bf(a.y); wa.z = f2bf(a.z); wa.w = f2bf(a.w);
            wc.x = f2bf(c.x); wc.y = f2bf(c.y); wc.z = f2bf(c.z); wc.w = f2bf(c.w);
            *(ushort4*)(rowp + c0)       = wa;
            *(ushort4*)(rowp + 136 + c0) = wc;
        }
        sW3[(t & 1) * 128 + (t >> 1)] = W3[t];   // [k][c] -> [c][k]
    }
    __syncthreads();               // hi/hj visible

    // ---------------- Phase B: layer 1 (M=128, N=256, K=512) ----------------
    const unsigned short* w1p[4];
#pragma unroll
    for (int nt = 0; nt < 4; nt++) w1p[nt] = W1T + (nb + nt * 16 + lrow) * 512 + quad * 8;

    f32x4 acc[8][4];
#pragma unroll
    for (int mt = 0; mt < 8; mt++)
#pragma unroll
        for (int nt = 0; nt < 4; nt++)
            acc[mt][nt] = (f32x4){0.f, 0.f, 0.f, 0.f};

    int aoff[8];
#pragma unroll
    for (int mt = 0; mt < 8; mt++) aoff[mt] = (mt * 16 + lrow) * 268 + quad * 8;

    // hi chunks (k 0..127)
#pragma unroll 1
    for (int ks = 0; ks < 4; ks++) {
        bf16x8 bv[4], av[8];
#pragma unroll
        for (int nt = 0; nt < 4; nt++) bv[nt] = *(const bf16x8*)(w1p[nt] + ks * 32);
#pragma unroll
        for (int mt = 0; mt < 8; mt++) av[mt] = *(const bf16x8*)(sH + aoff[mt] + ks * 32);
#pragma unroll
        for (int mt = 0; mt < 8; mt++)
#pragma unroll
            for (int nt = 0; nt < 4; nt++)
                acc[mt][nt] = __builtin_amdgcn_mfma_f32_16x16x32_bf16(av[mt], bv[nt], acc[mt][nt], 0, 0, 0);
    }
    // hj chunks (k 128..255)
#pragma unroll 1
    for (int ks = 0; ks < 4; ks++) {
        bf16x8 bv[4], av[8];
#pragma unroll
        for (int nt = 0; nt < 4; nt++) bv[nt] = *(const bf16x8*)(w1p[nt] + (ks + 4) * 32);
#pragma unroll
        for (int mt = 0; mt < 8; mt++) av[mt] = *(const bf16x8*)(sH + aoff[mt] + 136 + ks * 32);
#pragma unroll
        for (int mt = 0; mt < 8; mt++)
#pragma unroll
            for (int nt = 0; nt < 4; nt++)
                acc[mt][nt] = __builtin_amdgcn_mfma_f32_16x16x32_bf16(av[mt], bv[nt], acc[mt][nt], 0, 0, 0);
    }
    // diff chunks (k 256..383)
#pragma unroll 1
    for (int ks = 0; ks < 4; ks++) {
        bf16x8 bv[4], av[8];
#pragma unroll
        for (int nt = 0; nt < 4; nt++) bv[nt] = *(const bf16x8*)(w1p[nt] + (ks + 8) * 32);
#pragma unroll
        for (int mt = 0; mt < 8; mt++) {
            uint4 ua = *(const uint4*)(sH + aoff[mt] + ks * 32);
            uint4 ub = *(const uint4*)(sH + aoff[mt] + 136 + ks * 32);
            uint4 rr;
            rr.x = comb(ua.x, ub.x, true);
            rr.y = comb(ua.y, ub.y, true);
            rr.z = comb(ua.z, ub.z, true);
            rr.w = comb(ua.w, ub.w, true);
            av[mt] = __builtin_bit_cast(bf16x8, rr);
        }
#pragma unroll
        for (int mt = 0; mt < 8; mt++)
#pragma unroll
            for (int nt = 0; nt < 4; nt++)
                acc[mt][nt] = __builtin_amdgcn_mfma_f32_16x16x32_bf16(av[mt], bv[nt], acc[mt][nt], 0, 0, 0);
    }
    // prod chunks (k 384..511)
#pragma unroll 1
    for (int ks = 0; ks < 4; ks++) {
        bf16x8 bv[4], av[8];
#pragma unroll
        for (int nt = 0; nt < 4; nt++) bv[nt] = *(const bf16x8*)(w1p[nt] + (ks + 12) * 32);
#pragma unroll
        for (int mt = 0; mt < 8; mt++) {
            uint4 ua = *(const uint4*)(sH + aoff[mt] + ks * 32);
            uint4 ub = *(const uint4*)(sH + aoff[mt] + 136 + ks * 32);
            uint4 rr;
            rr.x = comb(ua.x, ub.x, false);
            rr.y = comb(ua.y, ub.y, false);
            rr.z = comb(ua.z, ub.z, false);
            rr.w = comb(ua.w, ub.w, false);
            av[mt] = __builtin_bit_cast(bf16x8, rr);
        }
#pragma unroll
        for (int mt = 0; mt < 8; mt++)
#pragma unroll
            for (int nt = 0; nt < 4; nt++)
                acc[mt][nt] = __builtin_amdgcn_mfma_f32_16x16x32_bf16(av[mt], bv[nt], acc[mt][nt], 0, 0, 0);
    }

    // ---------------- Phase C: relu+bias -> x1 bf16 (overlay sH) ----------------
    float b1v[4];
#pragma unroll
    for (int nt = 0; nt < 4; nt++) b1v[nt] = b1[nb + nt * 16 + lrow];

    __syncthreads();               // all layer-1 reads of sH done
    unsigned short* sx1 = sH;      // [128][268], cols 0..255
#pragma unroll
    for (int mt = 0; mt < 8; mt++)
#pragma unroll
        for (int nt = 0; nt < 4; nt++)
#pragma unroll
            for (int i = 0; i < 4; i++) {
                int row = mt * 16 + quad * 4 + i;    // C/D: row = quad*4 + reg
                int col = nb + nt * 16 + lrow;       //      col = lane&15
                float v = acc[mt][nt][i] + b1v[nt];
                v = v > 0.f ? v : 0.f;
                sx1[row * 268 + col] = f2bf(v);
            }
    __syncthreads();               // x1 complete

    // ---------------- Phase D: layer 2 (M=128, N=128, K=256) ----------------
    const unsigned short* w2p[2];
#pragma unroll
    for (int nt = 0; nt < 2; nt++) w2p[nt] = W2T + (nb2 + nt * 16 + lrow) * 256 + quad * 8;

    f32x4 acc2[8][2];
#pragma unroll
    for (int mt = 0; mt < 8; mt++)
#pragma unroll
        for (int nt = 0; nt < 2; nt++)
            acc2[mt][nt] = (f32x4){0.f, 0.f, 0.f, 0.f};

#pragma unroll 1
    for (int ks = 0; ks < 8; ks++) {
        bf16x8 bv2[2], av2[8];
#pragma unroll
        for (int nt = 0; nt < 2; nt++) bv2[nt] = *(const bf16x8*)(w2p[nt] + ks * 32);
#pragma unroll
        for (int mt = 0; mt < 8; mt++) av2[mt] = *(const bf16x8*)(sx1 + aoff[mt] + ks * 32);
#pragma unroll
        for (int mt = 0; mt < 8; mt++)
#pragma unroll
            for (int nt = 0; nt < 2; nt++)
                acc2[mt][nt] = __builtin_amdgcn_mfma_f32_16x16x32_bf16(av2[mt], bv2[nt], acc2[mt][nt], 0, 0, 0);
    }

    // ---------------- Phase E: relu+bias -> x2 bf16 (overlay) ----------------
    float b2v[2];
#pragma unroll
    for (int nt = 0; nt < 2; nt++) b2v[nt] = b2[nb2 + nt * 16 + lrow];

    __syncthreads();               // all layer-2 reads of x1 done
    unsigned short* sx2 = sH;      // [128][140] (70 dw stride, gcd 2 -> free)
#pragma unroll
    for (int mt = 0; mt < 8; mt++)
#pragma unroll
        for (int nt = 0; nt < 2; nt++)
#pragma unroll
            for (int i = 0; i < 4; i++) {
                int row = mt * 16 + quad * 4 + i;
                int col = nb2 + nt * 16 + lrow;
                float v = acc2[mt][nt][i] + b2v[nt];
                v = v > 0.f ? v : 0.f;
                sx2[row * 140 + col] = f2bf(v);
            }
    __syncthreads();

    // ---------------- Phase F: layer 3 (N=2), one thread per (row,class) ------
    {
        int r = t >> 1;            // edge row 0..127
        int c = t & 1;             // class
        const unsigned short* xr = sx2 + r * 140;
        const float* w3c = sW3 + c * 128;
        float s = 0.f;
#pragma unroll
        for (int j = 0; j < 16; j++) {
            uint4 v = *(const uint4*)(xr + j * 8);
            const float* w = w3c + j * 8;
            s += bflo(v.x) * w[0] + bfhi(v.x) * w[1]
               + bflo(v.y) * w[2] + bfhi(v.y) * w[3]
               + bflo(v.z) * w[4] + bfhi(v.z) * w[5]
               + bflo(v.w) * w[6] + bfhi(v.w) * w[7];
        }
        int e = e0 + r;
        if (e < E) out[e * 2 + c] = s + b3[c];
    }
}

extern "C" void kernel_launch(void* const* d_in, const int* in_sizes, int n_in,
                              void* d_out, int out_size, void* d_ws, size_t ws_size,
                              hipStream_t stream) {
    const float* node = (const float*)d_in[0];
    const int* src    = (const int*)d_in[1];
    const int* dst    = (const int*)d_in[2];
    const float* W1   = (const float*)d_in[3];
    const float* b1   = (const float*)d_in[4];
    const float* W2   = (const float*)d_in[5];
    const float* b2   = (const float*)d_in[6];
    const float* W3   = (const float*)d_in[7];
    const float* b3   = (const float*)d_in[8];
    float* out = (float*)d_out;
    const int E = in_sizes[1];

    unsigned short* W1T = (unsigned short*)d_ws;       // [256][512] bf16
    unsigned short* W2T = W1T + 512 * 256;             // [128][256] bf16

    hipLaunchKernelGGL(prep_w1, dim3(512), dim3(256), 0, stream, W1, W1T);
    hipLaunchKernelGGL(prep_w2, dim3(128), dim3(256), 0, stream, W2, W2T);
    const int nblk = (E + 127) / 128;
    hipLaunchKernelGGL(fused_mlp, dim3(nblk), dim3(256), 0, stream,
                       node, src, dst, W1T, b1, W2T, b2, W3, b3, out, E);
}

// Round 7
// 438.160 us; speedup vs baseline: 3.8541x; 1.0288x over previous
//
#include <hip/hip_runtime.h>

// EntityLinker fused edge-MLP for MI355X (gfx950).
// Round 7: dedup diff/prod synthesis (R6: every wave redundantly synthesized
// all 8 m-tiles' A-fragments -> VALUBusy 35%).
//   - Layer-1 K split in halves: half-1 reads hi|hj; then a cooperative
//     staging phase computes diff/prod ONCE per block and overwrites hi|hj
//     in place; half-2 reads staged data with plain ds_read_b128.
//   - All f32->bf16 via +0x8000 bias (2 ops) / v_perm pair-pack.
//   - M=128/block, 2 WG/CU, rolled K-loops (no-spill recipe from R6).

#define H 128

typedef __bf16 bf16x8 __attribute__((ext_vector_type(8)));
typedef float f32x4 __attribute__((ext_vector_type(4)));

__device__ __forceinline__ unsigned short f2bf(float f) {
    unsigned u = __builtin_bit_cast(unsigned, f);
    u += 0x7FFFu + ((u >> 16) & 1u);   // RNE (prep kernels only)
    return (unsigned short)(u >> 16);
}
__device__ __forceinline__ float bfhi(unsigned u) {
    return __builtin_bit_cast(float, u & 0xffff0000u);
}
__device__ __forceinline__ float bflo(unsigned u) {
    return __builtin_bit_cast(float, u << 16);
}
// pack two f32 -> bf16x2 (round-nearest-ties-away via +0x8000, v_perm pack)
__device__ __forceinline__ unsigned pk2(float r0, float r1) {
    unsigned u0 = __builtin_bit_cast(unsigned, r0) + 0x8000u;
    unsigned u1 = __builtin_bit_cast(unsigned, r1) + 0x8000u;
    return __builtin_amdgcn_perm(u1, u0, 0x07060302u);  // hi16(u1)<<16 | hi16(u0)
}
// |a-b| or a*b on packed bf16x2 -> packed bf16x2
__device__ __forceinline__ unsigned comb(unsigned ua, unsigned ub, bool isdiff) {
    float a0 = bflo(ua), a1 = bfhi(ua);
    float b0 = bflo(ub), b1 = bfhi(ub);
    float r0 = isdiff ? fabsf(a0 - b0) : a0 * b0;
    float r1 = isdiff ? fabsf(a1 - b1) : a1 * b1;
    return pk2(r0, r1);
}
__device__ __forceinline__ unsigned short cvt1(float v) {   // scalar 2-op cvt
    unsigned u = __builtin_bit_cast(unsigned, v) + 0x8000u;
    return (unsigned short)(u >> 16);
}

__global__ void prep_w1(const float* __restrict__ W1, unsigned short* __restrict__ W1T) {
    int idx = blockIdx.x * 256 + threadIdx.x;      // 131072
    int n = idx >> 9;
    int k = idx & 511;
    W1T[idx] = f2bf(W1[k * 256 + n]);              // W1 is [512][256] (in,out)
}

__global__ void prep_w2(const float* __restrict__ W2, unsigned short* __restrict__ W2T) {
    int idx = blockIdx.x * 256 + threadIdx.x;      // 32768
    int n = idx >> 8;
    int k = idx & 255;
    W2T[idx] = f2bf(W2[k * 128 + n]);              // W2 is [256][128]
}

__launch_bounds__(256, 2)
__global__ void fused_mlp(const float* __restrict__ node,
                          const int* __restrict__ src,
                          const int* __restrict__ dst,
                          const unsigned short* __restrict__ W1T,  // [256][512] bf16
                          const float* __restrict__ b1,
                          const unsigned short* __restrict__ W2T,  // [128][256] bf16
                          const float* __restrict__ b2,
                          const float* __restrict__ W3,            // [128][2] f32
                          const float* __restrict__ b3,
                          float* __restrict__ out,                 // [E][2] f32
                          int E) {
    // sH: [128][268] bf16. Region P (cols 0..127): hi, later diff.
    //                      Region Q (cols 136..263): hj, later prod.
    // Overlays: x1 [128][268] cols 0..255 after layer 1; x2 [128][140] after layer 2.
    __shared__ __align__(16) unsigned short sH[128 * 268];   // 68608 B
    __shared__ __align__(16) float sW3[256];                 // [c][128]

    const int t = threadIdx.x;
    const int e0 = blockIdx.x * 128;

    const int lane = t & 63;
    const int wv = t >> 6;
    const int quad = lane >> 4;
    const int lrow = lane & 15;
    const int nb = wv * 64;        // layer-1 N-slice
    const int nb2 = wv * 32;       // layer-2 N-slice

    // ---------------- Phase A: gather hi/hj -> LDS (bf16, pair-packed) ----------
    {
        int r = t >> 1;            // edge row 0..127
        int p = t & 1;             // 64-col half
        int e = e0 + r;
        int ec = e < E ? e : (E - 1);
        const float* hi = node + (long)src[ec] * H + p * 64;
        const float* hj = node + (long)dst[ec] * H + p * 64;
        unsigned short* rowp = sH + r * 268;
#pragma unroll
        for (int b = 0; b < 16; b++) {
            float4 a = ((const float4*)hi)[b];
            float4 c = ((const float4*)hj)[b];
            int c0 = p * 64 + b * 4;
            uint2 wa, wc;
            wa.x = pk2(a.x, a.y); wa.y = pk2(a.z, a.w);
            wc.x = pk2(c.x, c.y); wc.y = pk2(c.z, c.w);
            *(uint2*)(rowp + c0)       = wa;
            *(uint2*)(rowp + 136 + c0) = wc;
        }
        sW3[(t & 1) * 128 + (t >> 1)] = W3[t];   // [k][c] -> [c][k]
    }
    __syncthreads();               // hi/hj visible

    // ---------------- Phase B: layer 1 (M=128, N=256, K=512) ----------------
    const unsigned short* w1p[4];
#pragma unroll
    for (int nt = 0; nt < 4; nt++) w1p[nt] = W1T + (nb + nt * 16 + lrow) * 512 + quad * 8;

    f32x4 acc[8][4];
#pragma unroll
    for (int mt = 0; mt < 8; mt++)
#pragma unroll
        for (int nt = 0; nt < 4; nt++)
            acc[mt][nt] = (f32x4){0.f, 0.f, 0.f, 0.f};

    int aoff[8];
#pragma unroll
    for (int mt = 0; mt < 8; mt++) aoff[mt] = (mt * 16 + lrow) * 268 + quad * 8;

    // K-half 1: k 0..255  (A = hi | hj, as stored)
#pragma unroll 1
    for (int ks = 0; ks < 8; ks++) {
        const int ao = (ks < 4) ? ks * 32 : 136 + (ks - 4) * 32;
        bf16x8 bv[4], av[8];
#pragma unroll
        for (int nt = 0; nt < 4; nt++) bv[nt] = *(const bf16x8*)(w1p[nt] + ks * 32);
#pragma unroll
        for (int mt = 0; mt < 8; mt++) av[mt] = *(const bf16x8*)(sH + aoff[mt] + ao);
#pragma unroll
        for (int mt = 0; mt < 8; mt++)
#pragma unroll
            for (int nt = 0; nt < 4; nt++)
                acc[mt][nt] = __builtin_amdgcn_mfma_f32_16x16x32_bf16(av[mt], bv[nt], acc[mt][nt], 0, 0, 0);
    }

    __syncthreads();               // half-1 reads of hi/hj complete

    // ------------- Staging: diff -> region P, prod -> region Q (in place) -------
    {
        int r = t >> 1;
        int c0 = (t & 1) * 64;
        unsigned short* rowp = sH + r * 268;
#pragma unroll
        for (int j = 0; j < 8; j++) {
            uint4 ua = *(const uint4*)(rowp + c0 + j * 8);
            uint4 ub = *(const uint4*)(rowp + 136 + c0 + j * 8);
            uint4 dd, pp;
            dd.x = comb(ua.x, ub.x, true);  dd.y = comb(ua.y, ub.y, true);
            dd.z = comb(ua.z, ub.z, true);  dd.w = comb(ua.w, ub.w, true);
            pp.x = comb(ua.x, ub.x, false); pp.y = comb(ua.y, ub.y, false);
            pp.z = comb(ua.z, ub.z, false); pp.w = comb(ua.w, ub.w, false);
            *(uint2*)(rowp + c0 + j * 8)           = (uint2){dd.x, dd.y};
            *(uint2*)(rowp + c0 + j * 8 + 4)       = (uint2){dd.z, dd.w};
            *(uint2*)(rowp + 136 + c0 + j * 8)     = (uint2){pp.x, pp.y};
            *(uint2*)(rowp + 136 + c0 + j * 8 + 4) = (uint2){pp.z, pp.w};
        }
    }
    __syncthreads();               // diff/prod staged

    // K-half 2: k 256..511 (A = diff | prod, same addressing as half-1)
#pragma unroll 1
    for (int ks = 0; ks < 8; ks++) {
        const int ao = (ks < 4) ? ks * 32 : 136 + (ks - 4) * 32;
        bf16x8 bv[4], av[8];
#pragma unroll
        for (int nt = 0; nt < 4; nt++) bv[nt] = *(const bf16x8*)(w1p[nt] + (ks + 8) * 32);
#pragma unroll
        for (int mt = 0; mt < 8; mt++) av[mt] = *(const bf16x8*)(sH + aoff[mt] + ao);
#pragma unroll
        for (int mt = 0; mt < 8; mt++)
#pragma unroll
            for (int nt = 0; nt < 4; nt++)
                acc[mt][nt] = __builtin_amdgcn_mfma_f32_16x16x32_bf16(av[mt], bv[nt], acc[mt][nt], 0, 0, 0);
    }

    // ---------------- Phase C: relu+bias -> x1 bf16 (overlay sH) ----------------
    float b1v[4];
#pragma unroll
    for (int nt = 0; nt < 4; nt++) b1v[nt] = b1[nb + nt * 16 + lrow];

    __syncthreads();               // all layer-1 reads of sH done
    unsigned short* sx1 = sH;      // [128][268], cols 0..255
#pragma unroll
    for (int mt = 0; mt < 8; mt++)
#pragma unroll
        for (int nt = 0; nt < 4; nt++)
#pragma unroll
            for (int i = 0; i < 4; i++) {
                int row = mt * 16 + quad * 4 + i;    // C/D: row = quad*4 + reg
                int col = nb + nt * 16 + lrow;       //      col = lane&15
                float v = acc[mt][nt][i] + b1v[nt];
                v = v > 0.f ? v : 0.f;
                sx1[row * 268 + col] = cvt1(v);
            }
    __syncthreads();               // x1 complete

    // ---------------- Phase D: layer 2 (M=128, N=128, K=256) ----------------
    const unsigned short* w2p[2];
#pragma unroll
    for (int nt = 0; nt < 2; nt++) w2p[nt] = W2T + (nb2 + nt * 16 + lrow) * 256 + quad * 8;

    f32x4 acc2[8][2];
#pragma unroll
    for (int mt = 0; mt < 8; mt++)
#pragma unroll
        for (int nt = 0; nt < 2; nt++)
            acc2[mt][nt] = (f32x4){0.f, 0.f, 0.f, 0.f};

#pragma unroll 1
    for (int ks = 0; ks < 8; ks++) {
        bf16x8 bv2[2], av2[8];
#pragma unroll
        for (int nt = 0; nt < 2; nt++) bv2[nt] = *(const bf16x8*)(w2p[nt] + ks * 32);
#pragma unroll
        for (int mt = 0; mt < 8; mt++) av2[mt] = *(const bf16x8*)(sx1 + aoff[mt] + ks * 32);
#pragma unroll
        for (int mt = 0; mt < 8; mt++)
#pragma unroll
            for (int nt = 0; nt < 2; nt++)
                acc2[mt][nt] = __builtin_amdgcn_mfma_f32_16x16x32_bf16(av2[mt], bv2[nt], acc2[mt][nt], 0, 0, 0);
    }

    // ---------------- Phase E: relu+bias -> x2 bf16 (overlay) ----------------
    float b2v[2];
#pragma unroll
    for (int nt = 0; nt < 2; nt++) b2v[nt] = b2[nb2 + nt * 16 + lrow];

    __syncthreads();               // all layer-2 reads of x1 done
    unsigned short* sx2 = sH;      // [128][140] (70 dw stride, gcd 2 -> free)
#pragma unroll
    for (int mt = 0; mt < 8; mt++)
#pragma unroll
        for (int nt = 0; nt < 2; nt++)
#pragma unroll
            for (int i = 0; i < 4; i++) {
                int row = mt * 16 + quad * 4 + i;
                int col = nb2 + nt * 16 + lrow;
                float v = acc2[mt][nt][i] + b2v[nt];
                v = v > 0.f ? v : 0.f;
                sx2[row * 140 + col] = cvt1(v);
            }
    __syncthreads();

    // ---------------- Phase F: layer 3 (N=2), one thread per (row,class) ------
    {
        int r = t >> 1;            // edge row 0..127
        int c = t & 1;             // class
        const unsigned short* xr = sx2 + r * 140;
        const float* w3c = sW3 + c * 128;
        float s = 0.f;
#pragma unroll
        for (int j = 0; j < 16; j++) {
            uint4 v = *(const uint4*)(xr + j * 8);
            const float* w = w3c + j * 8;
            s += bflo(v.x) * w[0] + bfhi(v.x) * w[1]
               + bflo(v.y) * w[2] + bfhi(v.y) * w[3]
               + bflo(v.z) * w[4] + bfhi(v.z) * w[5]
               + bflo(v.w) * w[6] + bfhi(v.w) * w[7];
        }
        int e = e0 + r;
        if (e < E) out[e * 2 + c] = s + b3[c];
    }
}

extern "C" void kernel_launch(void* const* d_in, const int* in_sizes, int n_in,
                              void* d_out, int out_size, void* d_ws, size_t ws_size,
                              hipStream_t stream) {
    const float* node = (const float*)d_in[0];
    const int* src    = (const int*)d_in[1];
    const int* dst    = (const int*)d_in[2];
    const float* W1   = (const float*)d_in[3];
    const float* b1   = (const float*)d_in[4];
    const float* W2   = (const float*)d_in[5];
    const float* b2   = (const float*)d_in[6];
    const float* W3   = (const float*)d_in[7];
    const float* b3   = (const float*)d_in[8];
    float* out = (float*)d_out;
    const int E = in_sizes[1];

    unsigned short* W1T = (unsigned short*)d_ws;       // [256][512] bf16
    unsigned short* W2T = W1T + 512 * 256;             // [128][256] bf16

    hipLaunchKernelGGL(prep_w1, dim3(512), dim3(256), 0, stream, W1, W1T);
    hipLaunchKernelGGL(prep_w2, dim3(128), dim3(256), 0, stream, W2, W2T);
    const int nblk = (E + 127) / 128;
    hipLaunchKernelGGL(fused_mlp, dim3(nblk), dim3(256), 0, stream,
                       node, src, dst, W1T, b1, W2T, b2, W3, b3, out, E);
}